// Round 3
// baseline (176.092 us; speedup 1.0000x reference)
//
#include <hip/hip_runtime.h>
#include <math.h>

#define NEG 0.2f
#define EPSV 1e-5f

typedef _Float16 v8h __attribute__((ext_vector_type(8)));
typedef _Float16 v4h __attribute__((ext_vector_type(4)));
typedef _Float16 v2h __attribute__((ext_vector_type(2)));
typedef __fp16   f16x2 __attribute__((ext_vector_type(2)));
typedef float    v4f __attribute__((ext_vector_type(4)));

__device__ __forceinline__ float lrelu(float v) { return fmaxf(v, NEG * v); }
__device__ __forceinline__ v4f lrelu4(v4f v) {
    return __builtin_elementwise_max(v, v * NEG);
}
__device__ __forceinline__ v2h lreluh2(v2h v) {
    return __builtin_elementwise_max(v, v * (_Float16)NEG);
}

// cvt_pkrtz returns __fp16x2; bit-cast to _Float16x2 (same layout)
__device__ __forceinline__ v2h pk(float a, float b) {
    union { f16x2 i; v2h o; } u;
    u.i = __builtin_amdgcn_cvt_pkrtz(a, b);
    return u.o;
}

#define MFMA16(a, b, c) __builtin_amdgcn_mfma_f32_16x16x16f16((a), (b), (c), 0, 0, 0)

// Round 17: eliminate the pos_h/attn_h LDS round-trip entirely.
// Key fact (proven in-kernel by the gate path since R15): for
// mfma_f32_16x16x16_f16 the C/D lane layout (lane(p,q) holds rows 4q+i of
// col p) EQUALS the B-operand layout (lane(p,q) holds B[k=4q+i][col p]).
// So packed pos_h / attn_h MFMA outputs are directly usable as B-operands
// in registers. The old consume used 16x16x32 MFMAs whose B-frag needs
// k=8q..8q+7 (different lane grouping) -> that forced the LDS redistribution.
// Splitting pos_enc into 4x MFMA16 (K=16) per output tile removes:
//   - PHB/AHB dbuf (23.5 KB LDS)  -> LDS 37,888 -> 14,336 B
//   - 5 ds_write + 3 ds_read per k, the produce-ahead pipeline, and the
//     stride-72 bank conflicts (5.15M -> expect ~0)
// W2 A-frags stay in LDS at the SAME addresses/banks (stride-40, 2-way-free);
// only the staging-time element permutation changes: each b128 read now
// yields two K=16 A-frags (ck pair) instead of one K=32 frag.
// asm memory clobber stays: without it LICM hoists the 8 b128 W2 reads +
// 6 WH frag reads into ~44 VGPRs and blows the (256,4) budget (R9/R15 mode).
__global__ __launch_bounds__(256, 4)
void gsl_mfma(const float* __restrict__ x,
              const float* __restrict__ trans_w, const float* __restrict__ trans_g,
              const float* __restrict__ trans_b, const float* __restrict__ trans_m,
              const float* __restrict__ trans_v,
              const float* __restrict__ pos_w1, const float* __restrict__ pos_g,
              const float* __restrict__ pos_b, const float* __restrict__ pos_m,
              const float* __restrict__ pos_v, const float* __restrict__ pos_w2,
              const float* __restrict__ pos_b2,
              const float* __restrict__ gate_w1, const float* __restrict__ gate_g,
              const float* __restrict__ gate_b, const float* __restrict__ gate_m,
              const float* __restrict__ gate_v, const float* __restrict__ gate_w2,
              const float* __restrict__ gate_b2,
              const float* __restrict__ attn_w1, const float* __restrict__ attn_g,
              const float* __restrict__ attn_b, const float* __restrict__ attn_m,
              const float* __restrict__ attn_v, const float* __restrict__ attn_w2,
              const float* __restrict__ attn_b2,
              float* __restrict__ out)
{
    __shared__ _Float16 WH[1920];   // WP1 4x(16x20) | WA1 16x20 | WG1 16x20
    __shared__ _Float16 W2L[5120];  // pos_w2: 8 tiles x 16p x stride40,
                                    // inner 32 elems permuted into 2x K=16 A-frags
    __shared__ float    PB2[64];

    const int tid  = threadIdx.x;
    const int wv   = tid >> 6;
    const int lane = tid & 63;
    const int p    = lane & 15;
    const int q    = lane >> 4;

    const int b  = blockIdx.x >> 7;
    const int n0 = ((blockIdx.x & 127) << 6) | (wv << 4);
    const int n  = n0 | p;

    // ---- stage pos_w2 A-frags into W2L ----
    // read addr (unchanged from R16): lane(p,q) v8h at tile*640 + p*40 + 8q.
    // element ii within a row now maps to source col:
    //   c = (t&1)*32 + ((ii&7)>>2)*16 + ((ii>>3)<<2) + (ii&3)
    // so v8h lo4 = A_ck(2h)[p][4q+i], hi4 = A_ck(2h+1)[p][4q+i].
    #pragma unroll
    for (int e = 0; e < 16; ++e) {
        int idx = tid * 16 + e;              // 4096 elements
        int t   = idx >> 9;                  // tile (mt*2+h)
        int rem = idx & 511;
        int pp  = rem >> 5;
        int ii  = rem & 31;
        int c   = (t & 1) * 32 + ((ii & 7) >> 2) * 16 + ((ii >> 3) << 2) + (ii & 3);
        W2L[t * 640 + pp * 40 + ii] =
            (_Float16)pos_w2[((t >> 1) * 16 + pp) * 64 + c];
    }

    // ---- stage produce-side weights in block-shared LDS (rows stride 20h) ----
    if (tid < 64) {
        const int c = tid;
        float sp = pos_g[c] * rsqrtf(pos_v[c] + EPSV);
        float bp = pos_b[c] - pos_m[c] * sp;
        _Float16* row = WH + (c >> 4) * 320 + (c & 15) * 20;
        for (int k = 0; k < 20; ++k) {
            float v = (k >= 3 && k < 6) ? pos_w1[c * 3 + (k - 3)] * sp
                                        : ((k == 6) ? bp : 0.f);
            row[k] = (_Float16)v;
        }
        PB2[c] = pos_b2[c];
    } else if (tid < 80) {
        const int j = tid - 64;
        float sa = attn_g[j] * rsqrtf(attn_v[j] + EPSV);
        float ba = attn_b[j] - attn_m[j] * sa;
        _Float16* row = WH + 1280 + j * 20;
        for (int k = 0; k < 20; ++k)
            row[k] = (_Float16)((k < 6) ? attn_w1[j * 6 + k] * sa
                                        : ((k == 6) ? ba : 0.f));
    } else if (tid < 96) {
        const int j = tid - 80;
        float sg = gate_g[j] * rsqrtf(gate_v[j] + EPSV);
        float bg = gate_b[j] - gate_m[j] * sg;
        _Float16* row = WH + 1600 + j * 20;
        for (int k = 0; k < 20; ++k)
            row[k] = (_Float16)((k < 6) ? gate_w1[j * 6 + k] * sg
                                        : ((k == 6) ? bg : 0.f));
    }

    // ---- persistent A-frags: WTf/WA2f (2 VGPRs each) + WG2f broadcast ----
    v4h WTf[4], WA2f[4], WG2f;
    #pragma unroll
    for (int mt = 0; mt < 4; ++mt) {
        const int ch = mt * 16 + p;
        #pragma unroll
        for (int i = 0; i < 4; ++i)
            WA2f[mt][i] = (_Float16)attn_w2[ch * 16 + q * 4 + i];
        float st = trans_g[ch] * rsqrtf(trans_v[ch] + EPSV);
        float bt = trans_b[ch] - trans_m[ch] * st;
        #pragma unroll
        for (int i = 0; i < 4; ++i) {
            int k = q * 4 + i;
            float v = (k < 6) ? trans_w[ch * 6 + k] * st : ((k == 6) ? bt : 0.f);
            WTf[mt][i] = (_Float16)v;
        }
    }
    #pragma unroll
    for (int i = 0; i < 4; ++i)
        WG2f[i] = (_Float16)gate_w2[4 * q + i];   // A[row][k]=gate_w2[k] broadcast
    const float gb2v = gate_b2[0];

    __syncthreads();   // W2L/WH/PB2 visible to all waves

    const _Float16* const WP1p = WH + p * 20 + q * 4;          // + mt*320
    const _Float16* const WA1p = WH + 1280 + p * 20 + q * 4;
    const _Float16* const WG1p = WH + 1600 + p * 20 + q * 4;
    const _Float16* const W2Lp = W2L + p * 40 + q * 8;         // + tile*640
    const float* const    PB2p = PB2 + 4 * q;                  // + mt*16

    const v4f zero = {0.f, 0.f, 0.f, 0.f};
    v4f den[4], num[4], cmx[4];
    #pragma unroll
    for (int mt = 0; mt < 4; ++mt) {
        den[mt] = zero; num[mt] = zero;
        cmx[mt] = (v4f){-3.4e38f, -3.4e38f, -3.4e38f, -3.4e38f};
    }

    // ---- per-lane channel streams (only the 4 this lane consumes) ----
    const float* xb = x + ((size_t)(b * 6) * 8192 + n) * 20;
    const int hi = q & 1;   // q>=2 dups q&1 (A-side k>=8 rows are zero)
    const float* const s0p = xb + (size_t)(hi ? 4 : 0) * 163840;
    const float* const s1p = xb + (size_t)(hi ? 5 : 1) * 163840;
    const float* const s2p = xb + (size_t)(hi ? 4 : 2) * 163840;  // hi: L1 dup
    const float* const s3p = xb + (size_t)(hi ? 5 : 3) * 163840;  // hi: L1 dup

    // build v4h B-frag; hi lanes' high half is the constant (1.0, 0.0)
    auto mk = [&](float a, float bb, float cc, float dd) -> v4h {
        v2h lo = pk(a, bb);
        v2h hh = pk(cc, dd);
        if (hi) { union { unsigned u; v2h h; } t; t.u = 0x00003C00u; hh = t.h; }
        return (v4h){lo.x, lo.y, hh.x, hh.y};
    };

    float c0 = s0p[0], c1 = s1p[0], c2 = s2p[0], c3 = s3p[0];

    #pragma unroll 1
    for (int k = 0; k < 20; ++k) {
        // prevent LICM from hoisting in-loop LDS reads into registers
        asm volatile("" ::: "memory");

        v4h xv = mk(c0, c1, c2, c3);
        if (k < 19) {
            c0 = s0p[k + 1]; c1 = s1p[k + 1];
            c2 = s2p[k + 1]; c3 = s3p[k + 1];
        }

        // ---- hidden layers: MFMA outputs stay in registers (C==B layout) ----
        v4h phB[4];
        #pragma unroll
        for (int mt = 0; mt < 4; ++mt) {
            v4f php = MFMA16(*(const v4h*)(WP1p + mt * 320), xv, zero);
            union { v4h v; v2h h[2]; } u;
            u.h[0] = lreluh2(pk(php[0], php[1]));
            u.h[1] = lreluh2(pk(php[2], php[3]));
            phB[mt] = u.v;
        }
        v4f ahp = MFMA16(*(const v4h*)WA1p, xv, zero);
        union { v4h v; v2h h[2]; } ua;
        ua.h[0] = lreluh2(pk(ahp[0], ahp[1]));
        ua.h[1] = lreluh2(pk(ahp[2], ahp[3]));
        const v4h ahB = ua.v;

        // gate: MFMA reduction (broadcast A) -> every lane gets its col's logit
        v4f ghp = MFMA16(*(const v4h*)WG1p, xv, zero);
        union { v4h v; v2h h[2]; } ug;
        ug.h[0] = lreluh2(pk(ghp[0], ghp[1]));
        ug.h[1] = lreluh2(pk(ghp[2], ghp[3]));
        v4f gav = MFMA16(WG2f, ug.v, zero);
        const float gate = 1.f / (1.f + __expf(-(gav[0] + gb2v)));

        // ---- consume: pos_enc as 4x K=16 MFMA chain per output tile ----
        #pragma unroll
        for (int mt = 0; mt < 4; ++mt) {
            union { v8h v; v4h h[2]; } w2a, w2b;
            w2a.v = *(const v8h*)(W2Lp + (mt * 2 + 0) * 640);  // ck0 | ck1
            w2b.v = *(const v8h*)(W2Lp + (mt * 2 + 1) * 640);  // ck2 | ck3
            v4f pe = MFMA16(w2a.h[0], phB[0], *(const v4f*)(PB2p + mt * 16));
            pe = MFMA16(w2a.h[1], phB[1], pe);
            pe = MFMA16(w2b.h[0], phB[2], pe);
            pe = MFMA16(w2b.h[1], phB[3], pe);
            v4f tfa = MFMA16(WTf[mt], xv, zero);
            v4f tfv = lrelu4(tfa) + pe;
            pe = MFMA16(WA2f[mt], ahB, pe);   // attn logits (K=16)
            v4f e;
            #pragma unroll
            for (int r = 0; r < 4; ++r) e[r] = __expf(pe[r]);
            den[mt] += e;
            num[mt] += tfv * e;
            cmx[mt] = __builtin_elementwise_max(cmx[mt], tfv * gate);
        }
    }

    // write out: lane owns channels mt*16 + 4q + r for its point n
    #pragma unroll
    for (int mt = 0; mt < 4; ++mt) {
        #pragma unroll
        for (int r = 0; r < 4; ++r) {
            const int ch = mt * 16 + 4 * q + r;
            out[((size_t)(b * 64 + ch)) * 8192 + n] =
                num[mt][r] / den[mt][r] + cmx[mt][r];
        }
    }
}

extern "C" void kernel_launch(void* const* d_in, const int* in_sizes, int n_in,
                              void* d_out, int out_size, void* d_ws, size_t ws_size,
                              hipStream_t stream) {
    const float* x       = (const float*)d_in[0];
    const float* trans_w = (const float*)d_in[1];
    const float* trans_g = (const float*)d_in[2];
    const float* trans_b = (const float*)d_in[3];
    const float* trans_m = (const float*)d_in[4];
    const float* trans_v = (const float*)d_in[5];
    const float* pos_w1  = (const float*)d_in[6];
    const float* pos_g   = (const float*)d_in[7];
    const float* pos_b   = (const float*)d_in[8];
    const float* pos_m   = (const float*)d_in[9];
    const float* pos_v   = (const float*)d_in[10];
    const float* pos_w2  = (const float*)d_in[11];
    const float* pos_b2  = (const float*)d_in[12];
    const float* gate_w1 = (const float*)d_in[13];
    const float* gate_g  = (const float*)d_in[14];
    const float* gate_b  = (const float*)d_in[15];
    const float* gate_m  = (const float*)d_in[16];
    const float* gate_v  = (const float*)d_in[17];
    const float* gate_w2 = (const float*)d_in[18];
    const float* gate_b2 = (const float*)d_in[19];
    const float* attn_w1 = (const float*)d_in[20];
    const float* attn_g  = (const float*)d_in[21];
    const float* attn_b  = (const float*)d_in[22];
    const float* attn_m  = (const float*)d_in[23];
    const float* attn_v  = (const float*)d_in[24];
    const float* attn_w2 = (const float*)d_in[25];
    const float* attn_b2 = (const float*)d_in[26];
    float* out = (float*)d_out;

    // 8 b * 128 blocks/b; block = 4 waves * 16 points
    gsl_mfma<<<1024, 256, 0, stream>>>(
        x, trans_w, trans_g, trans_b, trans_m, trans_v,
        pos_w1, pos_g, pos_b, pos_m, pos_v, pos_w2, pos_b2,
        gate_w1, gate_g, gate_b, gate_m, gate_v, gate_w2, gate_b2,
        attn_w1, attn_g, attn_b, attn_m, attn_v, attn_w2, attn_b2,
        out);
}